// Round 4
// baseline (431.448 us; speedup 1.0000x reference)
//
#include <hip/hip_runtime.h>

#define NB 512
#define NV 64
#define ND 32
#define NH 64
#define NE 4032

typedef short s16x8 __attribute__((ext_vector_type(8)));
typedef float f32x4 __attribute__((ext_vector_type(4)));
typedef unsigned int u32;

#define HLOG2PI 0.9189385332046727f
#define LOG2C   0.6931471805599453f

__device__ __forceinline__ unsigned short f2bf(float f){
  u32 u = __float_as_uint(f);
  u += 0x7FFFu + ((u >> 16) & 1u);
  return (unsigned short)(u >> 16);
}
__device__ __forceinline__ u32 pk2(float a, float b){
  return (u32)f2bf(a) | ((u32)f2bf(b) << 16);
}

// ---------------- setup: bucket + weight prep + x->bf16 (one launch) --------

__global__ __launch_bounds__(256) void k_setup(
    const int* __restrict__ recv, const int* __restrict__ send,
    const float* __restrict__ x,
    const float* __restrict__ m1w, const float* __restrict__ m2w,
    int* __restrict__ ebyv, int* __restrict__ sbyv,
    unsigned short* __restrict__ W1cm, unsigned short* __restrict__ W2cm,
    uint4* __restrict__ xbf)
{
  const int blk = blockIdx.x, t = threadIdx.x;
  if (blk == 0){
    __shared__ int cnt[NV];
    if (t < NV) cnt[t] = 0;
    __syncthreads();
    for (int e = t; e < NE; e += 256){
      int v = recv[e];
      int p = atomicAdd(&cnt[v], 1);
      ebyv[v*64 + p] = e;
      sbyv[v*64 + p] = send[e];
    }
    __syncthreads();
    if (t < NV){
      for (int s = cnt[t]; s < 64; s++){ ebyv[t*64 + s] = -1; sbyv[t*64 + s] = t; }
    }
  } else if (blk == 1){
    #pragma unroll
    for (int i = 0; i < 16; i++){
      int idx = i*256 + t; int k = idx >> 6, j = idx & 63;
      W1cm[j*64 + k] = f2bf(m1w[idx]);        // col-major [j][k]
    }
  } else if (blk == 2){
    #pragma unroll
    for (int i = 0; i < 16; i++){
      int idx = i*256 + t; int k = idx >> 6, j = idx & 63;
      W2cm[j*64 + k] = f2bf(m2w[idx]);
    }
  } else {
    int i = (blk - 3)*256 + t;                // 512 blocks -> 131072 chunks
    const float4* s = (const float4*)x + i*2;
    float4 a = s[0], b = s[1];
    xbf[i] = make_uint4(pk2(a.x,a.y), pk2(a.z,a.w), pk2(b.x,b.y), pk2(b.z,b.w));
  }
}

// ---------------- fused kernel: edge MLP + scatter + node MLP + heads --------
// one block per (b,v). Edge part: 64 rows (63 edges + dummy), 2 bf16 MFMA
// GEMMs with W-frags read straight from global (L1-resident, 16KB shared by
// all blocks). Then agg -> aug row -> f32 GEMV node MLP + heads, all in-block.

__global__ __launch_bounds__(256, 6) void k_msg(
    const unsigned short* __restrict__ xbf, const float* __restrict__ x,
    const float* __restrict__ edges,
    const int* __restrict__ ebyv, const int* __restrict__ sbyv,
    const unsigned short* __restrict__ W1cm, const unsigned short* __restrict__ W2cm,
    const float* __restrict__ b1g, const float* __restrict__ b2g,
    const float* __restrict__ f1w, const float* __restrict__ f1b,
    const float* __restrict__ f2w, const float* __restrict__ f2b,
    const float* __restrict__ muw, const float* __restrict__ mub,
    const float* __restrict__ lsw, const float* __restrict__ lsb,
    float* __restrict__ out0, float* __restrict__ out1, float* __restrict__ out_aug)
{
  __shared__ __align__(16) unsigned short A1[64*64];   // [edge-row][K=64] swz
  __shared__ __align__(16) unsigned short Hs[64*64];   // [edge-row][H=64] swz
  __shared__ __align__(16) float wrow[64];
  __shared__ __align__(16) float aggp[4][64];
  __shared__ __align__(16) float augf[96];
  __shared__ __align__(16) float part[4][64];
  __shared__ float h1f[64];
  __shared__ float h2f[64];

  const int tid = threadIdx.x;
  const int w = tid >> 6, lane = tid & 63;
  const int l16 = lane & 15, l4 = lane >> 4;
  const int b = blockIdx.x >> 6, v = blockIdx.x & 63;
  const int rowg = b*NV + v;

  // edge weights for this receiver (63 scattered gathers, used late)
  if (tid < 64){
    int e = ebyv[v*64 + tid];
    wrow[tid] = (e >= 0) ? edges[(b*NE + e)*2 + 1] : 0.0f;
  }

  // stage A1 (reg-staged, swizzled dest): 512 chunks = 64 rows x 8 chunks
  // row cols 0..31 = x[b,v], 32..63 = x[b,send_row]
  #pragma unroll
  for (int i = 0; i < 2; i++){
    int g = i*256 + tid;
    int row = g >> 3, c = g & 7;
    int node = (c < 4) ? (b*NV + v) : (b*NV + sbyv[v*64 + row]);
    uint4 xq = *(const uint4*)(xbf + node*32 + (c & 3)*8);
    *(uint4*)(A1 + row*64 + ((c ^ (row & 7)) << 3)) = xq;
  }
  __syncthreads();

  const int irow = w*16 + l16;     // this wave's edge-row group
  const int sw8 = irow & 7;
  const s16x8* W1q = (const s16x8*)W1cm;
  const s16x8* W2q = (const s16x8*)W2cm;

  // ---- layer 1: C[j][i] = mfma(A=W1 cols, B=A1 rows) ----
  f32x4 acc[4] = {};
  #pragma unroll
  for (int ks = 0; ks < 2; ks++){
    s16x8 bfrag = *(const s16x8*)(A1 + irow*64 + (((ks*4 + l4) ^ sw8) << 3));
    #pragma unroll
    for (int t = 0; t < 4; t++){
      s16x8 afrag = W1q[(t*16 + l16)*8 + ks*4 + l4];
      acc[t] = __builtin_amdgcn_mfma_f32_16x16x32_bf16(afrag, bfrag, acc[t], 0, 0, 0);
    }
  }
  // epilogue: thread holds j = t*16 + l4*4 + 0..3 for i = irow -> b64 writes
  {
    int off0 = irow*64 + (l4 & 1)*4;
    #pragma unroll
    for (int t = 0; t < 4; t++){
      float4 bq = *(const float4*)(b1g + t*16 + l4*4);
      float h0 = fmaxf(acc[t][0] + bq.x, 0.0f);
      float h1 = fmaxf(acc[t][1] + bq.y, 0.0f);
      float h2 = fmaxf(acc[t][2] + bq.z, 0.0f);
      float h3 = fmaxf(acc[t][3] + bq.w, 0.0f);
      int cj = 2*t + (l4 >> 1);
      *(uint2*)(Hs + off0 + ((cj ^ sw8) << 3)) = make_uint2(pk2(h0,h1), pk2(h2,h3));
    }
  }
  __syncthreads();

  // ---- layer 2: C[i][j] = mfma(A=Hs rows, B=W2 cols) ----
  f32x4 acc2[4] = {};
  #pragma unroll
  for (int ks = 0; ks < 2; ks++){
    s16x8 afrag = *(const s16x8*)(Hs + irow*64 + (((ks*4 + l4) ^ sw8) << 3));
    #pragma unroll
    for (int t = 0; t < 4; t++){
      s16x8 bfrag = W2q[(t*16 + l16)*8 + ks*4 + l4];
      acc2[t] = __builtin_amdgcn_mfma_f32_16x16x32_bf16(afrag, bfrag, acc2[t], 0, 0, 0);
    }
  }
  // weighted i-reduction: thread holds i = w*16 + l4*4 + r, j = t*16 + l16
  {
    float4 wq = *(const float4*)&wrow[w*16 + l4*4];
    #pragma unroll
    for (int t = 0; t < 4; t++){
      float b2v = b2g[t*16 + l16];
      float s = fmaxf(acc2[t][0] + b2v, 0.0f) * wq.x
              + fmaxf(acc2[t][1] + b2v, 0.0f) * wq.y
              + fmaxf(acc2[t][2] + b2v, 0.0f) * wq.z
              + fmaxf(acc2[t][3] + b2v, 0.0f) * wq.w;
      s += __shfl_xor(s, 16);
      s += __shfl_xor(s, 32);
      if (l4 == 0) aggp[w][t*16 + l16] = s;
    }
  }
  __syncthreads();

  // ---- aug row assembly (also output 3) ----
  if (tid < 64){
    float s = aggp[0][tid] + aggp[1][tid] + aggp[2][tid] + aggp[3][tid];
    augf[32 + tid] = s;
    out_aug[rowg*96 + 32 + tid] = s;
  } else if (tid < 96){
    float xv = x[rowg*ND + (tid - 64)];
    augf[tid - 64] = xv;
    out_aug[rowg*96 + (tid - 64)] = xv;
  }
  __syncthreads();

  // ---- node MLP as f32 GEMV (one row), all 4 waves on partials ----
  const int j = tid & 63, kq = tid >> 6;
  // fc1: K=96, 24 k's per wave
  {
    float p = 0.0f;
    #pragma unroll
    for (int k = 0; k < 24; k++)
      p += f1w[(kq*24 + k)*64 + j] * augf[kq*24 + k];
    part[kq][j] = p;
  }
  __syncthreads();
  if (tid < 64)
    h1f[j] = fmaxf(part[0][j] + part[1][j] + part[2][j] + part[3][j] + f1b[j], 0.0f);
  __syncthreads();
  // fc2: K=64, 16 k's per wave
  {
    float p = 0.0f;
    #pragma unroll
    for (int k = 0; k < 16; k++)
      p += f2w[(kq*16 + k)*64 + j] * h1f[kq*16 + k];
    part[kq][j] = p;
  }
  __syncthreads();
  if (tid < 64)
    h2f[j] = fmaxf(part[0][j] + part[1][j] + part[2][j] + part[3][j] + f2b[j], 0.0f);
  __syncthreads();

  // ---- heads + logp on wave 0: 16 outputs (mu 0..7, ls 8..15), K=64 ----
  if (tid < 64){
    const int out = tid >> 2, kb = (tid & 3)*16;
    float p = 0.0f;
    if (out < 8){
      #pragma unroll
      for (int k = 0; k < 16; k++) p += muw[(kb + k)*8 + out] * h2f[kb + k];
    } else {
      #pragma unroll
      for (int k = 0; k < 16; k++) p += lsw[(kb + k)*8 + (out - 8)] * h2f[kb + k];
    }
    p += __shfl_xor(p, 1);
    p += __shfl_xor(p, 2);
    float term = 0.0f;
    if ((tid & 3) == 0){
      if (out < 8){
        float mu = p + mub[out];
        out0[rowg*8 + out] = tanhf(mu);
        float xm = -2.0f * mu;
        float sp = fmaxf(xm, 0.0f) + log1pf(expf(-fabsf(xm)));  // softplus(-2mu)
        term = -2.0f * (LOG2C - mu - sp);
      } else {
        float lsv = fminf(fmaxf(p + lsb[out - 8], -3.0f), 1.0f);
        term = -lsv - HLOG2PI;
      }
    }
    term += __shfl_xor(term, 4);
    term += __shfl_xor(term, 8);
    term += __shfl_xor(term, 16);
    term += __shfl_xor(term, 32);
    if (tid == 0) out1[rowg] = term;
  }
}

// ---------------- launch -----------------------------------------------------

extern "C" void kernel_launch(void* const* d_in, const int* in_sizes, int n_in,
                              void* d_out, int out_size, void* d_ws, size_t ws_size,
                              hipStream_t stream) {
  const float* x     = (const float*)d_in[0];
  const float* edges = (const float*)d_in[1];
  const float* m1w   = (const float*)d_in[2];
  const float* m1b   = (const float*)d_in[3];
  const float* m2w   = (const float*)d_in[4];
  const float* m2b   = (const float*)d_in[5];
  const float* f1w   = (const float*)d_in[6];
  const float* f1b   = (const float*)d_in[7];
  const float* f2w   = (const float*)d_in[8];
  const float* f2b   = (const float*)d_in[9];
  const float* muw   = (const float*)d_in[10];
  const float* mub   = (const float*)d_in[11];
  const float* lsw   = (const float*)d_in[12];
  const float* lsb   = (const float*)d_in[13];
  const int*   send  = (const int*)d_in[14];
  const int*   recv  = (const int*)d_in[15];

  char* ws = (char*)d_ws;
  int* ebyv = (int*)ws;                                   // 16 KB
  int* sbyv = (int*)(ws + 16384);                         // 16 KB
  unsigned short* W1cm = (unsigned short*)(ws + 32768);   // 8 KB col-major
  unsigned short* W2cm = (unsigned short*)(ws + 40960);   // 8 KB col-major
  unsigned short* xbf  = (unsigned short*)(ws + 49152);   // 2 MB bf16 x

  float* out0    = (float*)d_out;        // tanh(mu) [B,V,8]
  float* out1    = out0 + NB*NV*8;       // logp [B,V]
  float* out_aug = out1 + NB*NV;         // aug [B,V,96]

  k_setup<<<3 + NB*NV*ND/2048, 256, 0, stream>>>(recv, send, x, m1w, m2w,
                                                 ebyv, sbyv, W1cm, W2cm, (uint4*)xbf);
  k_msg<<<NB*NV, 256, 0, stream>>>(xbf, x, edges, ebyv, sbyv, W1cm, W2cm,
                                   m1b, m2b, f1w, f1b, f2w, f2b,
                                   muw, mub, lsw, lsb, out0, out1, out_aug);
}

// Round 5
// 178.131 us; speedup vs baseline: 2.4221x; 2.4221x over previous
//
#include <hip/hip_runtime.h>

#define NB 512
#define NV 64
#define ND 32
#define NH 64
#define NE 4032

typedef short s16x8 __attribute__((ext_vector_type(8)));
typedef float f32x4 __attribute__((ext_vector_type(4)));
typedef unsigned int u32;

#define HLOG2PI 0.9189385332046727f
#define LOG2C   0.6931471805599453f

__device__ __forceinline__ unsigned short f2bf(float f){
  u32 u = __float_as_uint(f);
  u += 0x7FFFu + ((u >> 16) & 1u);
  return (unsigned short)(u >> 16);
}
__device__ __forceinline__ u32 pk2(float a, float b){
  return (u32)f2bf(a) | ((u32)f2bf(b) << 16);
}
// async global->LDS, 16B/lane; lds dst = wave-uniform base + lane*16
__device__ __forceinline__ void gload16(const void* g, void* l){
  __builtin_amdgcn_global_load_lds(
      (const __attribute__((address_space(1))) void*)g,
      (__attribute__((address_space(3))) void*)l, 16, 0, 0);
}

// ---------------- setup (1 launch, block-specialized) ------------------------
// blk0: bucket; blk1-5: weight bf16+transpose+swizzle; blk>=6: x -> bf16.
// weight layout: col j, element k at j*RL + ((k>>3)^(j&7))*8 + (k&7)

__global__ __launch_bounds__(256) void k_setup(
    const int* __restrict__ recv, const int* __restrict__ send,
    const float* __restrict__ x,
    const float* __restrict__ m1w, const float* __restrict__ m2w,
    const float* __restrict__ f1w, const float* __restrict__ f2w,
    const float* __restrict__ muw, const float* __restrict__ lsw,
    int* __restrict__ ebyv, int* __restrict__ sbyv,
    unsigned short* __restrict__ Wg, unsigned short* __restrict__ Fg,
    uint4* __restrict__ xbf)
{
  const int blk = blockIdx.x, t = threadIdx.x;
  if (blk == 0){
    __shared__ int cnt[NV];
    if (t < NV) cnt[t] = 0;
    __syncthreads();
    for (int e = t; e < NE; e += 256){
      int v = recv[e];
      int p = atomicAdd(&cnt[v], 1);
      ebyv[v*64 + p] = e;
      sbyv[v*64 + p] = send[e];
    }
    __syncthreads();
    if (t < NV){
      for (int s = cnt[t]; s < 64; s++){ ebyv[t*64 + s] = -1; sbyv[t*64 + s] = t; }
    }
  } else if (blk == 1){
    #pragma unroll
    for (int i = 0; i < 16; i++){ int idx = i*256 + t; int k = idx>>6, j = idx&63;
      Wg[j*64 + (((k>>3)^(j&7))<<3) + (k&7)] = f2bf(m1w[idx]); }
  } else if (blk == 2){
    #pragma unroll
    for (int i = 0; i < 16; i++){ int idx = i*256 + t; int k = idx>>6, j = idx&63;
      Wg[4096 + j*64 + (((k>>3)^(j&7))<<3) + (k&7)] = f2bf(m2w[idx]); }
  } else if (blk == 3){
    #pragma unroll
    for (int i = 0; i < 24; i++){ int idx = i*256 + t; int k = idx>>6, j = idx&63;
      Fg[j*128 + (((k>>3)^(j&7))<<3) + (k&7)] = f2bf(f1w[idx]); }   // [96][64]
  } else if (blk == 4){
    #pragma unroll
    for (int i = 0; i < 16; i++){ int idx = i*256 + t; int k = idx>>6, j = idx&63;
      Fg[8192 + j*64 + (((k>>3)^(j&7))<<3) + (k&7)] = f2bf(f2w[idx]); }
  } else if (blk == 5){
    #pragma unroll
    for (int i = 0; i < 4; i++){ int idx = i*256 + t; int k = idx>>4, j = idx&15;
      float s = (j < 8) ? muw[k*8 + j] : lsw[k*8 + (j-8)];
      Fg[12288 + j*64 + (((k>>3)^(j&7))<<3) + (k&7)] = f2bf(s); }
  } else {
    int i = (blk - 6)*256 + t;
    const float4* s = (const float4*)x + i*2;
    float4 a = s[0], b = s[1];
    xbf[i] = make_uint4(pk2(a.x,a.y), pk2(a.z,a.w), pk2(b.x,b.y), pk2(b.z,b.w));
  }
}

// ---------------- kernel 1: edge MLP, block = (v, 4 b's), wave owns b --------
// Stage once (1 barrier), then each wave: 64x64x64 L1 GEMM -> h in-place ->
// 64x64x64 L2 GEMM -> weighted i-reduce -> coalesced aug write. 64 MFMA/wave.

__global__ __launch_bounds__(256, 3) void k_msg(
    const unsigned short* __restrict__ xbf, const float* __restrict__ x,
    const float* __restrict__ edges,
    const int* __restrict__ ebyv, const int* __restrict__ sbyv,
    const unsigned short* __restrict__ Wg,
    const float* __restrict__ b1g, const float* __restrict__ b2g,
    float* __restrict__ out_aug)
{
  __shared__ __align__(16) unsigned short Wl[2*4096];   // W1 | W2 (swz image)
  __shared__ __align__(16) unsigned short A[4*4096];    // 4 b-tiles [64][64] swz
  __shared__ float wrow[4][64];
  __shared__ float agg[4][64];

  const int tid = threadIdx.x;
  const int w = tid >> 6, lane = tid & 63;
  const int l16 = lane & 15, l4 = lane >> 4;
  const int v = blockIdx.x & 63, bg = blockIdx.x >> 6;
  const int b = bg*4 + w;                 // this wave's batch row

  // W1|W2: 1024 chunks, linear (source already swizzle-imaged)
  {
    char* lb = (char*)Wl + w*64*16;
    #pragma unroll
    for (int i = 0; i < 4; i++)
      gload16(Wg + (i*256 + tid)*8, lb + i*256*16);
  }
  // edge weights: thread (w,lane) -> (b, slot lane)
  {
    int e = ebyv[v*64 + lane];
    wrow[w][lane] = (e >= 0) ? edges[(b*NE + e)*2 + 1] : 0.0f;
  }
  // A tiles: 2048 chunks; LDS linear, swizzle via permuted SOURCE chunk.
  // chunk g: bs=i>>1, row=(tid>>3)+(i&1)*32, cpos=tid&7, c=cpos^(row&7)
  {
    int r0 = tid >> 3;
    int s0 = sbyv[v*64 + r0];
    int s1 = sbyv[v*64 + r0 + 32];
    int c  = (tid & 7) ^ (r0 & 7);        // (row&7)==(r0&7) for both rows
    char* lb = (char*)A + w*64*16;
    #pragma unroll
    for (int i = 0; i < 8; i++){
      int sr   = (i & 1) ? s1 : s0;
      int node = (c < 4) ? v : sr;
      int ng   = (bg*4 + (i >> 1))*NV + node;
      gload16(xbf + ng*32 + (c & 3)*8, lb + i*256*16);
    }
  }
  __syncthreads();

  unsigned short* Ab = A + w*4096;        // this wave's tile (x, then h)
  const int sw = l16 & 7;

  // ---- layer 1: C[j][i] = mfma(A=W1 col j, B=x-tile row i), j,i in 4 tiles --
  f32x4 acc1[4][4] = {};                  // [jm][il]
  #pragma unroll
  for (int ks = 0; ks < 2; ks++){
    int ch = ((ks*4 + l4) ^ sw) << 3;
    s16x8 af[4], bf[4];
    #pragma unroll
    for (int jm = 0; jm < 4; jm++) af[jm] = *(const s16x8*)(Wl + (jm*16 + l16)*64 + ch);
    #pragma unroll
    for (int il = 0; il < 4; il++) bf[il] = *(const s16x8*)(Ab + (il*16 + l16)*64 + ch);
    #pragma unroll
    for (int jm = 0; jm < 4; jm++)
      #pragma unroll
      for (int il = 0; il < 4; il++)
        acc1[jm][il] = __builtin_amdgcn_mfma_f32_16x16x32_bf16(af[jm], bf[il], acc1[jm][il], 0, 0, 0);
  }
  // h epilogue in-place: thread holds j = jm*16+l4*4+r, i = il*16+l16.
  // Safe: all reads of stripe il are dataflow-deps of writes to stripe il.
  #pragma unroll
  for (int jm = 0; jm < 4; jm++){
    float4 bq = *(const float4*)(b1g + jm*16 + l4*4);
    int cj = jm*2 + (l4 >> 1);
    #pragma unroll
    for (int il = 0; il < 4; il++){
      float h0 = fmaxf(acc1[jm][il][0] + bq.x, 0.0f);
      float h1 = fmaxf(acc1[jm][il][1] + bq.y, 0.0f);
      float h2 = fmaxf(acc1[jm][il][2] + bq.z, 0.0f);
      float h3 = fmaxf(acc1[jm][il][3] + bq.w, 0.0f);
      int i = il*16 + l16;
      *(uint2*)(Ab + i*64 + ((cj ^ (i & 7)) << 3) + (l4 & 1)*4) =
          make_uint2(pk2(h0,h1), pk2(h2,h3));
    }
  }
  // ---- layer 2: C[i][j] = mfma(A=h row i, B=W2 col j) ----
  f32x4 acc2[4][4] = {};                  // [im][jt]
  #pragma unroll
  for (int ks = 0; ks < 2; ks++){
    int ch = ((ks*4 + l4) ^ sw) << 3;
    s16x8 af[4], bf[4];
    #pragma unroll
    for (int im = 0; im < 4; im++) af[im] = *(const s16x8*)(Ab + (im*16 + l16)*64 + ch);
    #pragma unroll
    for (int jt = 0; jt < 4; jt++) bf[jt] = *(const s16x8*)(Wl + 4096 + (jt*16 + l16)*64 + ch);
    #pragma unroll
    for (int im = 0; im < 4; im++)
      #pragma unroll
      for (int jt = 0; jt < 4; jt++)
        acc2[im][jt] = __builtin_amdgcn_mfma_f32_16x16x32_bf16(af[im], bf[jt], acc2[im][jt], 0, 0, 0);
  }
  // weighted i-reduce: thread holds i = im*16+l4*4+r (consecutive), j = jt*16+l16
  {
    float4 wq[4];
    #pragma unroll
    for (int im = 0; im < 4; im++) wq[im] = *(const float4*)&wrow[w][im*16 + l4*4];
    #pragma unroll
    for (int jt = 0; jt < 4; jt++){
      float b2v = b2g[jt*16 + l16];
      float s = 0.0f;
      #pragma unroll
      for (int im = 0; im < 4; im++){
        s += fmaxf(acc2[im][jt][0] + b2v, 0.0f) * wq[im].x;
        s += fmaxf(acc2[im][jt][1] + b2v, 0.0f) * wq[im].y;
        s += fmaxf(acc2[im][jt][2] + b2v, 0.0f) * wq[im].z;
        s += fmaxf(acc2[im][jt][3] + b2v, 0.0f) * wq[im].w;
      }
      s += __shfl_xor(s, 16);
      s += __shfl_xor(s, 32);
      if (l4 == 0) agg[w][jt*16 + l16] = s;
    }
  }
  // wave-local output (no block barrier): coalesced aug row write
  {
    int rowg = b*NV + v;
    out_aug[rowg*96 + 32 + lane] = agg[w][lane];
    if (lane < 32) out_aug[rowg*96 + lane] = x[rowg*ND + lane];
  }
}

// ---------------- kernel 2: node MLP + heads + logp (round-3, proven) --------

__global__ __launch_bounds__(256) void k_node(
    const float* __restrict__ aug,
    const unsigned short* __restrict__ Fg,
    const float* __restrict__ f1b, const float* __restrict__ f2b,
    const float* __restrict__ mub, const float* __restrict__ lsb,
    float* __restrict__ out0, float* __restrict__ out1)
{
  __shared__ __align__(16) unsigned short A [32*128];  // [row][K=96 pad 128] swz
  __shared__ __align__(16) unsigned short H1[32*64];
  __shared__ __align__(16) unsigned short H2[32*64];
  __shared__ __align__(16) unsigned short Wn[1664*8];  // F1 | F2 | HW
  unsigned short* F1 = Wn;
  unsigned short* F2 = Wn + 8192;
  unsigned short* HW = Wn + 12288;

  const int tid = threadIdx.x;
  const int w = tid >> 6, lane = tid & 63;
  const int l16 = lane & 15, l4 = lane >> 4;
  const int g = blockIdx.x;

  {
    char* lb = (char*)Wn + w*64*16;
    #pragma unroll
    for (int i = 0; i < 7; i++){
      if (i*256 + w*64 < 1664)
        gload16(Fg + (i*256 + w*64 + lane)*8, lb + i*256*16);
    }
  }
  #pragma unroll
  for (int i = 0; i < 2; i++){
    int c = i*256 + tid;
    if (c < 384){
      int row = (c*683) >> 13;     // c/12
      int cc = c - row*12;
      const float4* s = (const float4*)(aug + (g*32 + row)*96 + cc*8);
      float4 a = s[0], bq = s[1];
      *(uint4*)(A + row*128 + ((cc ^ (row & 7)) << 3)) =
          make_uint4(pk2(a.x,a.y), pk2(a.z,a.w), pk2(bq.x,bq.y), pk2(bq.z,bq.w));
    }
  }
  __syncthreads();

  const int it = w & 1, jb = (w >> 1) * 32;
  const int irow = it*16 + l16;
  const int sw = l16 & 7;

  float f1v[2][4], f2v[2][4];
  #pragma unroll
  for (int t = 0; t < 2; t++)
    #pragma unroll
    for (int r = 0; r < 4; r++){
      f1v[t][r] = f1b[jb + t*16 + l4*4 + r];
      f2v[t][r] = f2b[jb + t*16 + l4*4 + r];
    }

  f32x4 acc[2] = {};
  #pragma unroll
  for (int ks = 0; ks < 3; ks++){
    int ch = ((ks*4 + l4) ^ sw) << 3;
    s16x8 bfrag = *(const s16x8*)(A + irow*128 + ch);
    #pragma unroll
    for (int t = 0; t < 2; t++){
      s16x8 afrag = *(const s16x8*)(F1 + (jb + t*16 + l16)*128 + ch);
      acc[t] = __builtin_amdgcn_mfma_f32_16x16x32_bf16(afrag, bfrag, acc[t], 0, 0, 0);
    }
  }
  {
    int off0 = irow*64 + (l4 & 1)*4;
    #pragma unroll
    for (int t = 0; t < 2; t++){
      float h0 = fmaxf(acc[t][0] + f1v[t][0], 0.0f);
      float h1 = fmaxf(acc[t][1] + f1v[t][1], 0.0f);
      float h2 = fmaxf(acc[t][2] + f1v[t][2], 0.0f);
      float h3 = fmaxf(acc[t][3] + f1v[t][3], 0.0f);
      int j0 = jb + t*16 + l4*4;
      *(uint2*)(H1 + off0 + (((j0 >> 3) ^ (irow & 7)) << 3)) =
          make_uint2(pk2(h0,h1), pk2(h2,h3));
    }
  }
  __syncthreads();

  f32x4 acc2[2] = {};
  #pragma unroll
  for (int ks = 0; ks < 2; ks++){
    int ch = ((ks*4 + l4) ^ sw) << 3;
    s16x8 bfrag = *(const s16x8*)(H1 + irow*64 + ch);
    #pragma unroll
    for (int t = 0; t < 2; t++){
      s16x8 afrag = *(const s16x8*)(F2 + (jb + t*16 + l16)*64 + ch);
      acc2[t] = __builtin_amdgcn_mfma_f32_16x16x32_bf16(afrag, bfrag, acc2[t], 0, 0, 0);
    }
  }
  {
    int off0 = irow*64 + (l4 & 1)*4;
    #pragma unroll
    for (int t = 0; t < 2; t++){
      float h0 = fmaxf(acc2[t][0] + f2v[t][0], 0.0f);
      float h1 = fmaxf(acc2[t][1] + f2v[t][1], 0.0f);
      float h2 = fmaxf(acc2[t][2] + f2v[t][2], 0.0f);
      float h3 = fmaxf(acc2[t][3] + f2v[t][3], 0.0f);
      int j0 = jb + t*16 + l4*4;
      *(uint2*)(H2 + off0 + (((j0 >> 3) ^ (irow & 7)) << 3)) =
          make_uint2(pk2(h0,h1), pk2(h2,h3));
    }
  }
  __syncthreads();

  if (w < 2){
    const int ir = w*16 + l16;
    f32x4 acc3 = {};
    #pragma unroll
    for (int ks = 0; ks < 2; ks++){
      int ch = ((ks*4 + l4) ^ sw) << 3;
      s16x8 a = *(const s16x8*)(H2 + ir*64 + ch);
      s16x8 bb = *(const s16x8*)(HW + l16*64 + ch);
      acc3 = __builtin_amdgcn_mfma_f32_16x16x32_bf16(a, bb, acc3, 0, 0, 0);
    }
    float bias = (l16 < 8) ? mub[l16] : lsb[l16 - 8];
    float term[4];
    #pragma unroll
    for (int r = 0; r < 4; r++){
      int grow = g*32 + w*16 + l4*4 + r;
      float val = acc3[r] + bias;
      if (l16 < 8){
        out0[grow*8 + l16] = tanhf(val);
        float xm = -2.0f * val;
        float sp = fmaxf(xm, 0.0f) + log1pf(expf(-fabsf(xm)));  // softplus(-2mu)
        term[r] = -2.0f * (LOG2C - val - sp);
      } else {
        float lsv = fminf(fmaxf(val, -3.0f), 1.0f);
        term[r] = -lsv - HLOG2PI;
      }
    }
    #pragma unroll
    for (int r = 0; r < 4; r++){
      term[r] += __shfl_xor(term[r], 1);
      term[r] += __shfl_xor(term[r], 2);
      term[r] += __shfl_xor(term[r], 4);
      term[r] += __shfl_xor(term[r], 8);
    }
    if (l16 == 0){
      #pragma unroll
      for (int r = 0; r < 4; r++) out1[g*32 + w*16 + l4*4 + r] = term[r];
    }
  }
}

// ---------------- launch -----------------------------------------------------

extern "C" void kernel_launch(void* const* d_in, const int* in_sizes, int n_in,
                              void* d_out, int out_size, void* d_ws, size_t ws_size,
                              hipStream_t stream) {
  const float* x     = (const float*)d_in[0];
  const float* edges = (const float*)d_in[1];
  const float* m1w   = (const float*)d_in[2];
  const float* m1b   = (const float*)d_in[3];
  const float* m2w   = (const float*)d_in[4];
  const float* m2b   = (const float*)d_in[5];
  const float* f1w   = (const float*)d_in[6];
  const float* f1b   = (const float*)d_in[7];
  const float* f2w   = (const float*)d_in[8];
  const float* f2b   = (const float*)d_in[9];
  const float* muw   = (const float*)d_in[10];
  const float* mub   = (const float*)d_in[11];
  const float* lsw   = (const float*)d_in[12];
  const float* lsb   = (const float*)d_in[13];
  const int*   send  = (const int*)d_in[14];
  const int*   recv  = (const int*)d_in[15];

  char* ws = (char*)d_ws;
  int* ebyv = (int*)ws;                                   // 16 KB
  int* sbyv = (int*)(ws + 16384);                         // 16 KB
  unsigned short* Wg  = (unsigned short*)(ws + 32768);    // 16 KB: W1 | W2
  unsigned short* Fg  = (unsigned short*)(ws + 49152);    // 26 KB: F1 | F2 | HW
  unsigned short* xbf = (unsigned short*)(ws + 75776);    // 2 MB bf16 x

  float* out0    = (float*)d_out;        // tanh(mu) [B,V,8]
  float* out1    = out0 + NB*NV*8;       // logp [B,V]
  float* out_aug = out1 + NB*NV;         // aug [B,V,96]

  k_setup<<<6 + NB*NV*ND/2048, 256, 0, stream>>>(recv, send, x, m1w, m2w,
                                                 f1w, f2w, muw, lsw,
                                                 ebyv, sbyv, Wg, Fg, (uint4*)xbf);
  k_msg<<<NB*NV/4, 256, 0, stream>>>(xbf, x, edges, ebyv, sbyv, Wg,
                                     m1b, m2b, out_aug);
  k_node<<<NB*NV/32, 256, 0, stream>>>(out_aug, Fg, f1b, f2b, mub, lsb, out0, out1);
}

// Round 7
// 163.887 us; speedup vs baseline: 2.6326x; 1.0869x over previous
//
#include <hip/hip_runtime.h>

#define NB 512
#define NV 64
#define ND 32
#define NH 64
#define NE 4032

typedef short s16x8 __attribute__((ext_vector_type(8)));
typedef float f32x4 __attribute__((ext_vector_type(4)));
typedef unsigned int u32;

#define HLOG2PI 0.9189385332046727f
#define LOG2C   0.6931471805599453f

__device__ __forceinline__ unsigned short f2bf(float f){
  u32 u = __float_as_uint(f);
  u += 0x7FFFu + ((u >> 16) & 1u);
  return (unsigned short)(u >> 16);
}
__device__ __forceinline__ u32 pk2(float a, float b){
  return (u32)f2bf(a) | ((u32)f2bf(b) << 16);
}
// async global->LDS, 16B/lane; lds dst = wave-uniform base + lane*16
__device__ __forceinline__ void gload16(const void* g, void* l){
  __builtin_amdgcn_global_load_lds(
      (const __attribute__((address_space(1))) void*)g,
      (__attribute__((address_space(3))) void*)l, 16, 0, 0);
}

// ---------------- setup (1 launch, block-specialized) ------------------------
// Wg: W1_bot [64 j][32 k] swz f(j)=(j>>1)&3  |  W2 [64 j][64 k] swz f(j)=j&7
// Fg: F1 [64 j][128 k-pad] | F2 [64 j][64] | HW [16 j][64], swz f(j)=j&7

__global__ __launch_bounds__(256) void k_setup(
    const int* __restrict__ recv, const int* __restrict__ send,
    const float* __restrict__ x,
    const float* __restrict__ m1w, const float* __restrict__ m2w,
    const float* __restrict__ f1w, const float* __restrict__ f2w,
    const float* __restrict__ muw, const float* __restrict__ lsw,
    int* __restrict__ ebyv, int* __restrict__ sbyv,
    unsigned short* __restrict__ Wg, unsigned short* __restrict__ Fg,
    uint4* __restrict__ xbf)
{
  const int blk = blockIdx.x, t = threadIdx.x;
  if (blk == 0){
    __shared__ int cnt[NV];
    if (t < NV) cnt[t] = 0;
    __syncthreads();
    for (int e = t; e < NE; e += 256){
      int v = recv[e];
      int p = atomicAdd(&cnt[v], 1);
      ebyv[v*64 + p] = e;
      sbyv[v*64 + p] = send[e];
    }
    __syncthreads();
    if (t < NV){
      for (int s = cnt[t]; s < 64; s++){ ebyv[t*64 + s] = -1; sbyv[t*64 + s] = t; }
    }
  } else if (blk == 1){
    // W1 bottom half (k=32..63), K=32 image
    #pragma unroll
    for (int i = 0; i < 8; i++){ int idx = i*256 + t; int kk = idx>>6, j = idx&63;
      Wg[j*32 + (((kk>>3) ^ ((j>>1)&3))<<3) + (kk&7)] = f2bf(m1w[(32+kk)*64 + j]); }
  } else if (blk == 2){
    #pragma unroll
    for (int i = 0; i < 16; i++){ int idx = i*256 + t; int k = idx>>6, j = idx&63;
      Wg[2048 + j*64 + (((k>>3)^(j&7))<<3) + (k&7)] = f2bf(m2w[idx]); }
  } else if (blk == 3){
    #pragma unroll
    for (int i = 0; i < 24; i++){ int idx = i*256 + t; int k = idx>>6, j = idx&63;
      Fg[j*128 + (((k>>3)^(j&7))<<3) + (k&7)] = f2bf(f1w[idx]); }   // [96][64]
  } else if (blk == 4){
    #pragma unroll
    for (int i = 0; i < 16; i++){ int idx = i*256 + t; int k = idx>>6, j = idx&63;
      Fg[8192 + j*64 + (((k>>3)^(j&7))<<3) + (k&7)] = f2bf(f2w[idx]); }
  } else if (blk == 5){
    #pragma unroll
    for (int i = 0; i < 4; i++){ int idx = i*256 + t; int k = idx>>4, j = idx&15;
      float s = (j < 8) ? muw[k*8 + j] : lsw[k*8 + (j-8)];
      Fg[12288 + j*64 + (((k>>3)^(j&7))<<3) + (k&7)] = f2bf(s); }
  } else {
    int i = (blk - 6)*256 + t;
    const float4* s = (const float4*)x + i*2;
    float4 a = s[0], b = s[1];
    xbf[i] = make_uint4(pk2(a.x,a.y), pk2(a.z,a.w), pk2(b.x,b.y), pk2(b.z,b.w));
  }
}

// ---------------- kernel 1: edge MLP, block = (v, 4 b's), wave owns b --------
// Layer-1 K=32 (x_send only; x_recv@W1_top folded into b1_eff). x fragments
// direct global->VGPR. h handoff via 4KB/wave fragment-layout exchange buffer,
// ping-ponged over two j-halves. One block barrier total.

__global__ __launch_bounds__(256, 3) void k_msg(
    const unsigned short* __restrict__ xbf, const float* __restrict__ x,
    const float* __restrict__ edges,
    const int* __restrict__ ebyv, const int* __restrict__ sbyv,
    const unsigned short* __restrict__ Wg, const float* __restrict__ m1w,
    const float* __restrict__ b1g, const float* __restrict__ b2g,
    float* __restrict__ out_aug)
{
  __shared__ __align__(16) unsigned short WlA[6144];  // W1b[64][32] | W2[64][64]
  __shared__ __align__(16) char Hx[4][4096];          // per-wave h exchange
  __shared__ float wrowS[4][64];
  __shared__ float b1e[4][64];
  __shared__ float agg[4][64];

  const int tid = threadIdx.x;
  const int w = tid >> 6, lane = tid & 63;
  const int l16 = lane & 15, l4 = lane >> 4;
  const int v = blockIdx.x & 63, bg = blockIdx.x >> 6;
  const int b = bg*4 + w;                 // this wave's batch row

  // W staging: 768 x 16B chunks, linear (Wg is a pre-swizzled image)
  #pragma unroll
  for (int i = 0; i < 3; i++)
    gload16(Wg + (i*256 + tid)*8, (char*)WlA + i*4096 + w*1024);

  // x_send MFMA B-fragments straight to registers:
  // lane (l16,l4) holds row il*16+l16, k-octet l4 -> one 16B load each
  int sv[4];
  #pragma unroll
  for (int il = 0; il < 4; il++) sv[il] = sbyv[v*64 + il*16 + l16];
  s16x8 xf[4];
  #pragma unroll
  for (int il = 0; il < 4; il++)
    xf[il] = *(const s16x8*)(xbf + (b*NV + sv[il])*32 + l4*8);

  // edge weights for (b, slot lane)
  { int e = ebyv[v*64 + lane];
    wrowS[w][lane] = (e >= 0) ? edges[(b*NE + e)*2 + 1] : 0.0f; }

  // b1_eff[j] = b1[j] + x[b,v,:] @ W1_top[:,j]  (f32, coalesced over j=lane)
  { float s = b1g[lane];
    const float* xr = x + (b*NV + v)*ND;
    #pragma unroll
    for (int k = 0; k < 32; k++) s = fmaf(xr[k], m1w[k*64 + lane], s);
    b1e[w][lane] = s; }

  __syncthreads();

  const int ch32 = (l4 ^ ((l16 >> 1) & 3)) << 3;   // K=32 swizzle chunk
  const int sw8  = l16 & 7;
  char* Hw = Hx[w];
  const unsigned short* Wl2 = WlA + 2048;

  f32x4 acc2[4][4] = {};                  // [im][jt]
  #pragma unroll
  for (int half = 0; half < 2; half++){
    // ---- layer-1 half: h[:, half*32 .. +32) ----
    f32x4 a1[2][4] = {};
    #pragma unroll
    for (int jm = 0; jm < 2; jm++){
      s16x8 af = *(const s16x8*)(WlA + ((half*2 + jm)*16 + l16)*32 + ch32);
      #pragma unroll
      for (int il = 0; il < 4; il++)
        a1[jm][il] = __builtin_amdgcn_mfma_f32_16x16x32_bf16(af, xf[il], a1[jm][il], 0, 0, 0);
    }
    // bias+relu+pack -> exchange buffer (consumer-frag layout)
    #pragma unroll
    for (int jm = 0; jm < 2; jm++){
      float4 bq = *(const float4*)&b1e[w][(half*2 + jm)*16 + l4*4];
      #pragma unroll
      for (int il = 0; il < 4; il++){
        float h0 = fmaxf(a1[jm][il][0] + bq.x, 0.0f);
        float h1 = fmaxf(a1[jm][il][1] + bq.y, 0.0f);
        float h2 = fmaxf(a1[jm][il][2] + bq.z, 0.0f);
        float h3 = fmaxf(a1[jm][il][3] + bq.w, 0.0f);
        *(uint2*)(Hw + il*1024 + (jm*2 + (l4 >> 1))*256 + l16*16 + (l4 & 1)*8) =
            make_uint2(pk2(h0, h1), pk2(h2, h3));
      }
    }
    __builtin_amdgcn_sched_barrier(0);
    // ---- layer-2 partial K: linear lane*16 reads (conflict-free) ----
    s16x8 hf[4], wf[4];
    #pragma unroll
    for (int im = 0; im < 4; im++)
      hf[im] = *(const s16x8*)(Hw + im*1024 + lane*16);
    #pragma unroll
    for (int jt = 0; jt < 4; jt++)
      wf[jt] = *(const s16x8*)(Wl2 + (jt*16 + l16)*64 + (((half*4 + l4) ^ sw8) << 3));
    #pragma unroll
    for (int im = 0; im < 4; im++)
      #pragma unroll
      for (int jt = 0; jt < 4; jt++)
        acc2[im][jt] = __builtin_amdgcn_mfma_f32_16x16x32_bf16(hf[im], wf[jt], acc2[im][jt], 0, 0, 0);
    __builtin_amdgcn_sched_barrier(0);    // WAR: reads before next half's writes
  }

  // weighted i-reduce: thread holds i = im*16+l4*4+r, j = jt*16+l16
  {
    float4 wq[4];
    #pragma unroll
    for (int im = 0; im < 4; im++) wq[im] = *(const float4*)&wrowS[w][im*16 + l4*4];
    #pragma unroll
    for (int jt = 0; jt < 4; jt++){
      float b2v = b2g[jt*16 + l16];
      float s = 0.0f;
      #pragma unroll
      for (int im = 0; im < 4; im++){
        s += fmaxf(acc2[im][jt][0] + b2v, 0.0f) * wq[im].x;
        s += fmaxf(acc2[im][jt][1] + b2v, 0.0f) * wq[im].y;
        s += fmaxf(acc2[im][jt][2] + b2v, 0.0f) * wq[im].z;
        s += fmaxf(acc2[im][jt][3] + b2v, 0.0f) * wq[im].w;
      }
      s += __shfl_xor(s, 16);
      s += __shfl_xor(s, 32);
      if (l4 == 0) agg[w][jt*16 + l16] = s;
    }
  }
  __builtin_amdgcn_sched_barrier(0);
  // wave-local coalesced aug write
  {
    int rowg = b*NV + v;
    out_aug[rowg*96 + 32 + lane] = agg[w][lane];
    if (lane < 32) out_aug[rowg*96 + lane] = x[rowg*ND + lane];
  }
}

// ---------------- kernel 2: node MLP, wave-private 16 rows, 1 barrier --------

__global__ __launch_bounds__(256) void k_node(
    const float* __restrict__ aug,
    const unsigned short* __restrict__ Fg,
    const float* __restrict__ f1b, const float* __restrict__ f2b,
    const float* __restrict__ mub, const float* __restrict__ lsb,
    float* __restrict__ out0, float* __restrict__ out1)
{
  __shared__ __align__(16) unsigned short Wn[1664*8];  // F1 | F2 | HW (26KB)
  __shared__ __align__(16) char Hn[4][2048];           // per-wave exchange
  const unsigned short* F1 = Wn;
  const unsigned short* F2 = Wn + 8192;
  const unsigned short* HW = Wn + 12288;

  const int tid = threadIdx.x;
  const int w = tid >> 6, lane = tid & 63;
  const int l16 = lane & 15, l4 = lane >> 4;
  const int row = blockIdx.x*64 + w*16 + l16;   // this lane's B-column row

  #pragma unroll
  for (int i = 0; i < 7; i++){
    if (i*256 + w*64 < 1664)
      gload16(Fg + (i*256 + w*64 + lane)*8, (char*)Wn + i*4096 + w*1024);
  }
  // aug B-fragments (f32 -> bf16 in regs), K=96
  s16x8 bf1[3];
  #pragma unroll
  for (int ks = 0; ks < 3; ks++){
    const float4* p = (const float4*)(aug + row*96 + (ks*4 + l4)*8);
    float4 a = p[0], c = p[1];
    union { uint4 q; s16x8 v; } uu;
    uu.q = make_uint4(pk2(a.x,a.y), pk2(a.z,a.w), pk2(c.x,c.y), pk2(c.z,c.w));
    bf1[ks] = uu.v;
  }
  __syncthreads();

  const int sw8 = l16 & 7;
  char* Hw = Hn[w];

  // fc1: C[j][i] = mfma(F1 col j, aug row i)
  f32x4 a1[4] = {};
  #pragma unroll
  for (int ks = 0; ks < 3; ks++)
    #pragma unroll
    for (int jt = 0; jt < 4; jt++){
      s16x8 af = *(const s16x8*)(F1 + (jt*16 + l16)*128 + (((ks*4 + l4) ^ sw8) << 3));
      a1[jt] = __builtin_amdgcn_mfma_f32_16x16x32_bf16(af, bf1[ks], a1[jt], 0, 0, 0);
    }
  #pragma unroll
  for (int jt = 0; jt < 4; jt++){
    float4 bq = *(const float4*)(f1b + jt*16 + l4*4);
    float h0 = fmaxf(a1[jt][0] + bq.x, 0.0f);
    float h1 = fmaxf(a1[jt][1] + bq.y, 0.0f);
    float h2 = fmaxf(a1[jt][2] + bq.z, 0.0f);
    float h3 = fmaxf(a1[jt][3] + bq.w, 0.0f);
    *(uint2*)(Hw + (jt >> 1)*1024 + ((jt & 1)*2 + (l4 >> 1))*256 + l16*16 + (l4 & 1)*8) =
        make_uint2(pk2(h0, h1), pk2(h2, h3));
  }
  __builtin_amdgcn_sched_barrier(0);
  s16x8 bh[2];
  bh[0] = *(const s16x8*)(Hw + lane*16);
  bh[1] = *(const s16x8*)(Hw + 1024 + lane*16);
  // fc2
  f32x4 a2[4] = {};
  #pragma unroll
  for (int ks = 0; ks < 2; ks++)
    #pragma unroll
    for (int jt = 0; jt < 4; jt++){
      s16x8 af = *(const s16x8*)(F2 + (jt*16 + l16)*64 + (((ks*4 + l4) ^ sw8) << 3));
      a2[jt] = __builtin_amdgcn_mfma_f32_16x16x32_bf16(af, bh[ks], a2[jt], 0, 0, 0);
    }
  __builtin_amdgcn_sched_barrier(0);      // WAR before reusing Hw
  #pragma unroll
  for (int jt = 0; jt < 4; jt++){
    float4 bq = *(const float4*)(f2b + jt*16 + l4*4);
    float h0 = fmaxf(a2[jt][0] + bq.x, 0.0f);
    float h1 = fmaxf(a2[jt][1] + bq.y, 0.0f);
    float h2 = fmaxf(a2[jt][2] + bq.z, 0.0f);
    float h3 = fmaxf(a2[jt][3] + bq.w, 0.0f);
    *(uint2*)(Hw + (jt >> 1)*1024 + ((jt & 1)*2 + (l4 >> 1))*256 + l16*16 + (l4 & 1)*8) =
        make_uint2(pk2(h0, h1), pk2(h2, h3));
  }
  __builtin_amdgcn_sched_barrier(0);
  bh[0] = *(const s16x8*)(Hw + lane*16);
  bh[1] = *(const s16x8*)(Hw + 1024 + lane*16);
  // head: 16 cols (mu 0..7, ls 8..15)
  f32x4 a3 = {};
  #pragma unroll
  for (int ks = 0; ks < 2; ks++){
    s16x8 af = *(const s16x8*)(HW + l16*64 + (((ks*4 + l4) ^ sw8) << 3));
    a3 = __builtin_amdgcn_mfma_f32_16x16x32_bf16(af, bh[ks], a3, 0, 0, 0);
  }
  // epilogue: thread holds o = l4*4+r for its row
  float term = 0.0f;
  if (l4 < 2){
    float4 t;
    #pragma unroll
    for (int r = 0; r < 4; r++){
      int o = l4*4 + r;
      float mu = a3[r] + mub[o];
      ((float*)&t)[r] = tanhf(mu);
      float xm = -2.0f * mu;
      float sp = fmaxf(xm, 0.0f) + log1pf(expf(-fabsf(xm)));  // softplus(-2mu)
      term += -2.0f * (LOG2C - mu - sp);
    }
    *(float4*)(out0 + row*8 + l4*4) = t;
  } else {
    #pragma unroll
    for (int r = 0; r < 4; r++){
      float lsv = fminf(fmaxf(a3[r] + lsb[l4*4 + r - 8], -3.0f), 1.0f);
      term += -lsv - HLOG2PI;
    }
  }
  term += __shfl_xor(term, 16);
  term += __shfl_xor(term, 32);
  if (l4 == 0) out1[row] = term;
}

// ---------------- launch -----------------------------------------------------

extern "C" void kernel_launch(void* const* d_in, const int* in_sizes, int n_in,
                              void* d_out, int out_size, void* d_ws, size_t ws_size,
                              hipStream_t stream) {
  const float* x     = (const float*)d_in[0];
  const float* edges = (const float*)d_in[1];
  const float* m1w   = (const float*)d_in[2];
  const float* m1b   = (const float*)d_in[3];
  const float* m2w   = (const float*)d_in[4];
  const float* m2b   = (const float*)d_in[5];
  const float* f1w   = (const float*)d_in[6];
  const float* f1b   = (const float*)d_in[7];
  const float* f2w   = (const float*)d_in[8];
  const float* f2b   = (const float*)d_in[9];
  const float* muw   = (const float*)d_in[10];
  const float* mub   = (const float*)d_in[11];
  const float* lsw   = (const float*)d_in[12];
  const float* lsb   = (const float*)d_in[13];
  const int*   send  = (const int*)d_in[14];
  const int*   recv  = (const int*)d_in[15];

  char* ws = (char*)d_ws;
  int* ebyv = (int*)ws;                                   // 16 KB
  int* sbyv = (int*)(ws + 16384);                         // 16 KB
  unsigned short* Wg  = (unsigned short*)(ws + 32768);    // 12 KB: W1b | W2
  unsigned short* Fg  = (unsigned short*)(ws + 49152);    // 26 KB: F1 | F2 | HW
  unsigned short* xbf = (unsigned short*)(ws + 75776);    // 2 MB bf16 x

  float* out0    = (float*)d_out;        // tanh(mu) [B,V,8]
  float* out1    = out0 + NB*NV*8;       // logp [B,V]
  float* out_aug = out1 + NB*NV;         // aug [B,V,96]

  k_setup<<<6 + NB*NV*ND/2048, 256, 0, stream>>>(recv, send, x, m1w, m2w,
                                                 f1w, f2w, muw, lsw,
                                                 ebyv, sbyv, Wg, Fg, (uint4*)xbf);
  k_msg<<<NB*NV/4, 256, 0, stream>>>(xbf, x, edges, ebyv, sbyv, Wg, m1w,
                                     m1b, m2b, out_aug);
  k_node<<<NB*NV/64, 256, 0, stream>>>(out_aug, Fg, f1b, f2b, mub, lsb, out0, out1);
}